// Round 9
// baseline (165.606 us; speedup 1.0000x reference)
//
#include <hip/hip_runtime.h>
#include <hip/hip_bf16.h>

#define B_ 8
#define T_ 2048
#define C_ 768
#define H_ 64
#define BT_ (B_*T_)

typedef __attribute__((ext_vector_type(8))) short bf16x8;
typedef __attribute__((ext_vector_type(4))) float f32x4;

__device__ __forceinline__ unsigned short f2bf(float x) {
    __hip_bfloat16 h = __float2bfloat16(x);   // RNE
    return __builtin_bit_cast(unsigned short, h);
}

__device__ __forceinline__ bf16x8 cvt8(float4 a, float4 b) {
    bf16x8 r;
    r[0] = (short)f2bf(a.x); r[1] = (short)f2bf(a.y);
    r[2] = (short)f2bf(a.z); r[3] = (short)f2bf(a.w);
    r[4] = (short)f2bf(b.x); r[5] = (short)f2bf(b.y);
    r[6] = (short)f2bf(b.z); r[7] = (short)f2bf(b.w);
    return r;
}

// ------------- W prep (coalesced LDS transpose): WT[m*64+n][k] = bf16(W_m[k][n])
__global__ __launch_bounds__(256) void wprep(
    const float* __restrict__ Wq, const float* __restrict__ Wk,
    const float* __restrict__ Wv, unsigned short* __restrict__ WT)
{
    __shared__ float tile[64][65];
    const int bidx = blockIdx.x;             // 36 = 3 m * 12 k-tiles
    const int m = bidx / 12, kt = bidx % 12;
    const float* __restrict__ W = (m == 0) ? Wq : (m == 1) ? Wk : Wv;
    const int t = threadIdx.x;
    const int n = t & 63, kr = t >> 6;
    #pragma unroll
    for (int r = kr; r < 64; r += 4)
        tile[r][n] = W[(size_t)(kt * 64 + r) * H_ + n];   // coalesced 256B rows
    __syncthreads();
    const int n2 = t >> 2, k0 = (t & 3) * 16;
    #pragma unroll
    for (int g = 0; g < 4; g++) {
        ushort4 u;
        u.x = f2bf(tile[k0 + g * 4 + 0][n2]);
        u.y = f2bf(tile[k0 + g * 4 + 1][n2]);
        u.z = f2bf(tile[k0 + g * 4 + 2][n2]);
        u.w = f2bf(tile[k0 + g * 4 + 3][n2]);
        *(ushort4*)(WT + (size_t)(m * 64 + n2) * C_ + kt * 64 + k0 + g * 4) = u;
    }
}

// ------------- QKV via MFMA: 4-wave K-split, 16 tokens/block --------------------
// Wave w owns k in [192w, 192w+192): 6 chunks of 32. Per chunk: ONE batch of 14
// independent loads (2 x float4 + 12 W bf16x8) then 12 MFMAs. Block reads its 16
// x rows exactly once (no N-split: R7's FETCH 4x blowup). 1024 blocks x 4 waves
// -> 16 waves/CU = 4/SIMD: R8's counters showed 2/SIMD cannot hide the ~200cyc
// L2 batch latency (75 cyc busy per batch needs >=3 waves/SIMD).
__global__ __launch_bounds__(256, 4) void qkv_kernel(
    const float* __restrict__ x, const unsigned short* __restrict__ WT,
    unsigned short* __restrict__ qo, unsigned short* __restrict__ ko,
    unsigned short* __restrict__ vTo)
{
    __shared__ float mrg[3][64][49];         // stride 49: odd -> 2-way banks (free)
    const int tid  = threadIdx.x;
    const int w    = tid >> 6;               // k-quarter 0..3
    const int lane = tid & 63;
    const int q16  = lane & 15, quad = lane >> 4;
    const int rowBase = blockIdx.x << 4;
    const int row  = rowBase + q16;
    const int b    = rowBase >> 11, t0 = rowBase & (T_ - 1);

    const float* __restrict__ xp = x + (size_t)row * C_ + w * 192 + quad * 8;
    const unsigned short* __restrict__ wp = WT + (size_t)q16 * C_ + w * 192 + quad * 8;

    f32x4 acc[12] = {};
    #pragma unroll
    for (int c = 0; c < 6; c++) {
        const int kk = c * 32;
        float4 xa = *(const float4*)(xp + kk);
        float4 xb = *(const float4*)(xp + kk + 4);
        bf16x8 wf[12];
        #pragma unroll
        for (int f = 0; f < 12; f++)
            wf[f] = *(const bf16x8*)(wp + kk + (size_t)(f * 16) * C_);
        bf16x8 xf = cvt8(xa, xb);
        #pragma unroll
        for (int f = 0; f < 12; f++)
            acc[f] = __builtin_amdgcn_mfma_f32_16x16x32_bf16(wf[f], xf, acc[f], 0, 0, 0);
    }

    // ---- merge the four K-quarters (once per block)
    if (w > 0) {
        #pragma unroll
        for (int f = 0; f < 12; f++)
            #pragma unroll
            for (int r = 0; r < 4; r++) mrg[w - 1][lane][f * 4 + r] = acc[f][r];
    }
    __syncthreads();
    if (w == 0) {
        #pragma unroll
        for (int j = 0; j < 3; j++)
            #pragma unroll
            for (int f = 0; f < 12; f++)
                #pragma unroll
                for (int r = 0; r < 4; r++) acc[f][r] += mrg[j][lane][f * 4 + r];

        #pragma unroll
        for (int f = 0; f < 8; f++) {
            ushort4 u;
            u.x = f2bf(acc[f][0]); u.y = f2bf(acc[f][1]);
            u.z = f2bf(acc[f][2]); u.w = f2bf(acc[f][3]);
            unsigned short* __restrict__ dst = (f < 4) ? qo : ko;
            *(ushort4*)(dst + (size_t)row * H_ + (f & 3) * 16 + quad * 4) = u;
        }
        #pragma unroll
        for (int f = 8; f < 12; f++)
            #pragma unroll
            for (int r = 0; r < 4; r++) {
                int h = (f - 8) * 16 + quad * 4 + r;
                vTo[((size_t)(b * H_) + h) * T_ + t0 + q16] = f2bf(acc[f][r]);
            }
    }
}

// ------------- MFMA flash attention: 4 waves/block k-split, NO in-loop barriers -
__global__ __launch_bounds__(256) void attn_kernel(
    const unsigned short* __restrict__ qB, const unsigned short* __restrict__ kB,
    const unsigned short* __restrict__ vT, const float* __restrict__ mask,
    float* __restrict__ out)
{
    __shared__ __align__(16) unsigned short pS[4][16][88];  // wave-private P tiles
    __shared__ float oS[3][64][17];
    __shared__ float mlS[3][64][2];

    const int tid  = threadIdx.x;
    const int w    = tid >> 6;
    const int lane = tid & 63;
    const int q16  = lane & 15;
    const int quad = lane >> 4;
    const int bid  = blockIdx.x;
    const int b    = bid & 7;                    // batches interleaved
    const int qt   = 127 - (bid >> 3);           // heavy q-tiles first
    const int qrow = (qt << 4) + q16;

    const size_t qoff = ((size_t)(b * T_) + qrow) * H_ + quad * 8;
    bf16x8 qf0 = *(const bf16x8*)(qB + qoff);
    bf16x8 qf1 = *(const bf16x8*)(qB + qoff + 32);
    // fold 1/sqrt(64) and log2(e): softmax runs in base-2 domain
    const float maskv = mask[b * T_ + qrow] * 0.125f * 1.44269504f;

    f32x4 o[4] = {};
    float m_run = -__builtin_inff();
    float l_run = 0.f;

    const int niter = ((qt << 4) + 16 + 63) >> 6;   // 64-wide k tiles
    for (int kt = w; kt < niter; kt += 4) {
        const int kbase = kt << 6;

        // ---- K and V fragment loads (issued together; V covers softmax latency)
        bf16x8 kf[8], vf[8];
        #pragma unroll
        for (int sub = 0; sub < 4; sub++) {
            const unsigned short* kp = kB + ((size_t)(b * T_) + kbase + sub * 16 + q16) * H_ + quad * 8;
            kf[2 * sub]     = *(const bf16x8*)(kp);
            kf[2 * sub + 1] = *(const bf16x8*)(kp + 32);
        }
        #pragma unroll
        for (int ht = 0; ht < 4; ht++) {
            const unsigned short* vp = vT + ((size_t)(b * H_) + ht * 16 + q16) * T_ + kbase + quad * 8;
            vf[2 * ht]     = *(const bf16x8*)(vp);
            vf[2 * ht + 1] = *(const bf16x8*)(vp + 32);
        }

        // ---- S^T = K.Q^T : D[k_local][q]
        f32x4 sa[4] = {};
        #pragma unroll
        for (int sub = 0; sub < 4; sub++) {
            sa[sub] = __builtin_amdgcn_mfma_f32_16x16x32_bf16(kf[2 * sub],     qf0, sa[sub], 0, 0, 0);
            sa[sub] = __builtin_amdgcn_mfma_f32_16x16x32_bf16(kf[2 * sub + 1], qf1, sa[sub], 0, 0, 0);
        }

        // ---- reference semantics: s = mask*qk/8 (log2 dom); s==0 -> -inf; causal
        float s[16];
        #pragma unroll
        for (int sub = 0; sub < 4; sub++)
            #pragma unroll
            for (int r = 0; r < 4; r++) {
                int kidx = kbase + sub * 16 + quad * 4 + r;
                float sv = sa[sub][r] * maskv;
                sv = (sv == 0.f) ? -__builtin_inff() : sv;
                sv = (kidx > qrow) ? -__builtin_inff() : sv;
                s[sub * 4 + r] = sv;
            }

        // ---- online softmax (base-2). xor-16/32 reduce across the 4 lane-quads.
        float mx = s[0];
        #pragma unroll
        for (int i2 = 1; i2 < 16; i2++) mx = fmaxf(mx, s[i2]);
        mx = fmaxf(mx, __shfl_xor(mx, 16));
        mx = fmaxf(mx, __shfl_xor(mx, 32));
        float m_new = fmaxf(m_run, mx);
        float m_use = (m_new == -__builtin_inff()) ? 0.f : m_new;
        float alpha = exp2f(m_run - m_use);
        float p[16], psum = 0.f;
        #pragma unroll
        for (int i2 = 0; i2 < 16; i2++) { p[i2] = exp2f(s[i2] - m_use); psum += p[i2]; }
        psum += __shfl_xor(psum, 16);
        psum += __shfl_xor(psum, 32);
        l_run = l_run * alpha + psum;
        m_run = m_new;
        #pragma unroll
        for (int ht = 0; ht < 4; ht++)
            #pragma unroll
            for (int r = 0; r < 4; r++) o[ht][r] *= alpha;

        // ---- P^T -> wave-private LDS as P[q][k] bf16 (intra-wave: no barrier)
        #pragma unroll
        for (int sub = 0; sub < 4; sub++) {
            unsigned int lo = (unsigned int)f2bf(p[sub * 4 + 0]) | ((unsigned int)f2bf(p[sub * 4 + 1]) << 16);
            unsigned int hi = (unsigned int)f2bf(p[sub * 4 + 2]) | ((unsigned int)f2bf(p[sub * 4 + 3]) << 16);
            *(uint2*)&pS[w][q16][sub * 16 + quad * 4] = make_uint2(lo, hi);
        }
        bf16x8 pf0 = *(const bf16x8*)&pS[w][q16][quad * 8];
        bf16x8 pf1 = *(const bf16x8*)&pS[w][q16][32 + quad * 8];

        // ---- O^T += V^T.P^T
        #pragma unroll
        for (int ht = 0; ht < 4; ht++) {
            o[ht] = __builtin_amdgcn_mfma_f32_16x16x32_bf16(vf[2 * ht],     pf0, o[ht], 0, 0, 0);
            o[ht] = __builtin_amdgcn_mfma_f32_16x16x32_bf16(vf[2 * ht + 1], pf1, o[ht], 0, 0, 0);
        }
    }

    // ---- merge the 4 waves' online-softmax states
    if (w > 0) {
        mlS[w - 1][lane][0] = m_run;
        mlS[w - 1][lane][1] = l_run;
        #pragma unroll
        for (int ht = 0; ht < 4; ht++)
            #pragma unroll
            for (int r = 0; r < 4; r++) oS[w - 1][lane][ht * 4 + r] = o[ht][r];
    }
    __syncthreads();
    if (w == 0) {
        float mm[3], ll[3];
        float m = m_run;
        #pragma unroll
        for (int j = 0; j < 3; j++) {
            mm[j] = mlS[j][lane][0]; ll[j] = mlS[j][lane][1];
            m = fmaxf(m, mm[j]);
        }
        float mu = (m == -__builtin_inff()) ? 0.f : m;
        float a0 = exp2f(m_run - mu);
        float aj[3];
        float l = l_run * a0;
        #pragma unroll
        for (int j = 0; j < 3; j++) { aj[j] = exp2f(mm[j] - mu); l += ll[j] * aj[j]; }
        float invl = (l > 0.f) ? (1.f / l) : 0.f;   // fully-masked row -> 0
        #pragma unroll
        for (int ht = 0; ht < 4; ht++) {
            float4 ov;
            float vx = o[ht][0] * a0, vy = o[ht][1] * a0, vz = o[ht][2] * a0, vw2 = o[ht][3] * a0;
            #pragma unroll
            for (int j = 0; j < 3; j++) {
                vx += oS[j][lane][ht * 4 + 0] * aj[j];
                vy += oS[j][lane][ht * 4 + 1] * aj[j];
                vz += oS[j][lane][ht * 4 + 2] * aj[j];
                vw2 += oS[j][lane][ht * 4 + 3] * aj[j];
            }
            ov.x = vx * invl; ov.y = vy * invl; ov.z = vz * invl; ov.w = vw2 * invl;
            *(float4*)(out + ((size_t)(b * T_) + qrow) * H_ + ht * 16 + quad * 4) = ov;
        }
    }
}

extern "C" void kernel_launch(void* const* d_in, const int* in_sizes, int n_in,
                              void* d_out, int out_size, void* d_ws, size_t ws_size,
                              hipStream_t stream) {
    const float* x    = (const float*)d_in[0];
    const float* mask = (const float*)d_in[1];
    const float* Wq   = (const float*)d_in[2];
    const float* Wk   = (const float*)d_in[3];
    const float* Wv   = (const float*)d_in[4];
    float* out = (float*)d_out;

    unsigned short* qw = (unsigned short*)d_ws;            // bf16 [B,T,H]
    unsigned short* kw = qw + (size_t)BT_ * H_;            // bf16 [B,T,H]
    unsigned short* vw = kw + (size_t)BT_ * H_;            // bf16 [B,H,T]
    unsigned short* wt = vw + (size_t)BT_ * H_;            // bf16 [192][768]

    wprep<<<36, 256, 0, stream>>>(Wq, Wk, Wv, wt);
    qkv_kernel<<<BT_ / 16, 256, 0, stream>>>(x, wt, qw, kw, vw);
    attn_kernel<<<B_ * (T_ / 16), 256, 0, stream>>>(qw, kw, vw, mask, out);
}

// Round 10
// 144.477 us; speedup vs baseline: 1.1462x; 1.1462x over previous
//
#include <hip/hip_runtime.h>
#include <hip/hip_bf16.h>

#define B_ 8
#define T_ 2048
#define C_ 768
#define H_ 64
#define BT_ (B_*T_)

typedef __attribute__((ext_vector_type(8))) short bf16x8;
typedef __attribute__((ext_vector_type(4))) float f32x4;

__device__ __forceinline__ unsigned short f2bf(float x) {
    __hip_bfloat16 h = __float2bfloat16(x);   // RNE
    return __builtin_bit_cast(unsigned short, h);
}

__device__ __forceinline__ bf16x8 cvt8(float4 a, float4 b) {
    bf16x8 r;
    r[0] = (short)f2bf(a.x); r[1] = (short)f2bf(a.y);
    r[2] = (short)f2bf(a.z); r[3] = (short)f2bf(a.w);
    r[4] = (short)f2bf(b.x); r[5] = (short)f2bf(b.y);
    r[6] = (short)f2bf(b.z); r[7] = (short)f2bf(b.w);
    return r;
}

// ------------- W prep: emit W in EXACT MFMA A-fragment order ---------------------
// WTf[gc][f][lane][8]: gc = k-chunk (0..23, 32 k each), f = output row group
// (0..11 over q|k|v), lane = q16 + 16*quad. Element j holds
// W_m[k = gc*32 + quad*8 + j][n = (f*16+q16) & 63], m = (f*16+q16)>>6.
// Consumer load = base + lane*16B: contiguous 1KB, 8 full lines per instruction.
// R6-R9 all plateaued ~50us because each W load was a 16-line half-line gather.
__global__ __launch_bounds__(256) void wprep(
    const float* __restrict__ Wq, const float* __restrict__ Wk,
    const float* __restrict__ Wv, unsigned short* __restrict__ WTf)
{
    const int gc = blockIdx.x;               // 0..23
    const int t  = threadIdx.x;
    const int lane = t >> 2;                 // 0..63
    const int j0   = (t & 3) * 2;            // 0,2,4,6
    const int q16  = lane & 15, quad = lane >> 4;
    const int k    = gc * 32 + quad * 8 + j0;
    #pragma unroll
    for (int f = 0; f < 12; f++) {
        const int row = f * 16 + q16;        // 0..191
        const int m = row >> 6, n = row & 63;
        const float* __restrict__ W = (m == 0) ? Wq : (m == 1) ? Wk : Wv;
        ushort2 u;
        u.x = f2bf(W[(size_t)k * H_ + n]);
        u.y = f2bf(W[(size_t)(k + 1) * H_ + n]);
        *(ushort2*)(WTf + (((size_t)gc * 12 + f) * 64 + lane) * 8 + j0) = u;
    }
}

// ------------- QKV via MFMA: 4-wave K-split, fragment-ordered W loads -----------
// Wave w owns global chunks gc = w*6 .. w*6+5. Per chunk: 2 x float4 loads +
// 12 perfectly-coalesced W loads (1KB contiguous each), then 12 MFMAs.
// Block reads its 16 x rows exactly once. Merge K-quarters once via LDS.
__global__ __launch_bounds__(256, 4) void qkv_kernel(
    const float* __restrict__ x, const unsigned short* __restrict__ WTf,
    unsigned short* __restrict__ qo, unsigned short* __restrict__ ko,
    unsigned short* __restrict__ vTo)
{
    __shared__ float mrg[3][64][49];         // stride 49: odd -> 2-way banks (free)
    const int tid  = threadIdx.x;
    const int w    = tid >> 6;               // k-quarter 0..3
    const int lane = tid & 63;
    const int q16  = lane & 15, quad = lane >> 4;
    const int rowBase = blockIdx.x << 4;
    const int row  = rowBase + q16;
    const int b    = rowBase >> 11, t0 = rowBase & (T_ - 1);

    const float* __restrict__ xp = x + (size_t)row * C_ + w * 192 + quad * 8;

    f32x4 acc[12] = {};
    #pragma unroll
    for (int c = 0; c < 6; c++) {
        const int gc = w * 6 + c;
        const unsigned short* __restrict__ wpc = WTf + ((size_t)gc * 12) * 512 + lane * 8;
        float4 xa = *(const float4*)(xp + c * 32);
        float4 xb = *(const float4*)(xp + c * 32 + 4);
        bf16x8 wf[12];
        #pragma unroll
        for (int f = 0; f < 12; f++)
            wf[f] = *(const bf16x8*)(wpc + f * 512);
        bf16x8 xf = cvt8(xa, xb);
        #pragma unroll
        for (int f = 0; f < 12; f++)
            acc[f] = __builtin_amdgcn_mfma_f32_16x16x32_bf16(wf[f], xf, acc[f], 0, 0, 0);
    }

    // ---- merge the four K-quarters (once per block)
    if (w > 0) {
        #pragma unroll
        for (int f = 0; f < 12; f++)
            #pragma unroll
            for (int r = 0; r < 4; r++) mrg[w - 1][lane][f * 4 + r] = acc[f][r];
    }
    __syncthreads();
    if (w == 0) {
        #pragma unroll
        for (int j = 0; j < 3; j++)
            #pragma unroll
            for (int f = 0; f < 12; f++)
                #pragma unroll
                for (int r = 0; r < 4; r++) acc[f][r] += mrg[j][lane][f * 4 + r];

        #pragma unroll
        for (int f = 0; f < 8; f++) {
            ushort4 u;
            u.x = f2bf(acc[f][0]); u.y = f2bf(acc[f][1]);
            u.z = f2bf(acc[f][2]); u.w = f2bf(acc[f][3]);
            unsigned short* __restrict__ dst = (f < 4) ? qo : ko;
            *(ushort4*)(dst + (size_t)row * H_ + (f & 3) * 16 + quad * 4) = u;
        }
        #pragma unroll
        for (int f = 8; f < 12; f++)
            #pragma unroll
            for (int r = 0; r < 4; r++) {
                int h = (f - 8) * 16 + quad * 4 + r;
                vTo[((size_t)(b * H_) + h) * T_ + t0 + q16] = f2bf(acc[f][r]);
            }
    }
}

// ------------- MFMA flash attention: 4 waves/block k-split, NO in-loop barriers -
__global__ __launch_bounds__(256) void attn_kernel(
    const unsigned short* __restrict__ qB, const unsigned short* __restrict__ kB,
    const unsigned short* __restrict__ vT, const float* __restrict__ mask,
    float* __restrict__ out)
{
    __shared__ __align__(16) unsigned short pS[4][16][88];  // wave-private P tiles
    __shared__ float oS[3][64][17];
    __shared__ float mlS[3][64][2];

    const int tid  = threadIdx.x;
    const int w    = tid >> 6;
    const int lane = tid & 63;
    const int q16  = lane & 15;
    const int quad = lane >> 4;
    const int bid  = blockIdx.x;
    const int b    = bid & 7;                    // batches interleaved
    const int qt   = 127 - (bid >> 3);           // heavy q-tiles first
    const int qrow = (qt << 4) + q16;

    const size_t qoff = ((size_t)(b * T_) + qrow) * H_ + quad * 8;
    bf16x8 qf0 = *(const bf16x8*)(qB + qoff);
    bf16x8 qf1 = *(const bf16x8*)(qB + qoff + 32);
    // fold 1/sqrt(64) and log2(e): softmax runs in base-2 domain
    const float maskv = mask[b * T_ + qrow] * 0.125f * 1.44269504f;

    f32x4 o[4] = {};
    float m_run = -__builtin_inff();
    float l_run = 0.f;

    const int niter = ((qt << 4) + 16 + 63) >> 6;   // 64-wide k tiles
    for (int kt = w; kt < niter; kt += 4) {
        const int kbase = kt << 6;

        // ---- K and V fragment loads (issued together; V covers softmax latency)
        bf16x8 kf[8], vf[8];
        #pragma unroll
        for (int sub = 0; sub < 4; sub++) {
            const unsigned short* kp = kB + ((size_t)(b * T_) + kbase + sub * 16 + q16) * H_ + quad * 8;
            kf[2 * sub]     = *(const bf16x8*)(kp);
            kf[2 * sub + 1] = *(const bf16x8*)(kp + 32);
        }
        #pragma unroll
        for (int ht = 0; ht < 4; ht++) {
            const unsigned short* vp = vT + ((size_t)(b * H_) + ht * 16 + q16) * T_ + kbase + quad * 8;
            vf[2 * ht]     = *(const bf16x8*)(vp);
            vf[2 * ht + 1] = *(const bf16x8*)(vp + 32);
        }

        // ---- S^T = K.Q^T : D[k_local][q]
        f32x4 sa[4] = {};
        #pragma unroll
        for (int sub = 0; sub < 4; sub++) {
            sa[sub] = __builtin_amdgcn_mfma_f32_16x16x32_bf16(kf[2 * sub],     qf0, sa[sub], 0, 0, 0);
            sa[sub] = __builtin_amdgcn_mfma_f32_16x16x32_bf16(kf[2 * sub + 1], qf1, sa[sub], 0, 0, 0);
        }

        // ---- reference semantics: s = mask*qk/8 (log2 dom); s==0 -> -inf; causal
        float s[16];
        #pragma unroll
        for (int sub = 0; sub < 4; sub++)
            #pragma unroll
            for (int r = 0; r < 4; r++) {
                int kidx = kbase + sub * 16 + quad * 4 + r;
                float sv = sa[sub][r] * maskv;
                sv = (sv == 0.f) ? -__builtin_inff() : sv;
                sv = (kidx > qrow) ? -__builtin_inff() : sv;
                s[sub * 4 + r] = sv;
            }

        // ---- online softmax (base-2). xor-16/32 reduce across the 4 lane-quads.
        float mx = s[0];
        #pragma unroll
        for (int i2 = 1; i2 < 16; i2++) mx = fmaxf(mx, s[i2]);
        mx = fmaxf(mx, __shfl_xor(mx, 16));
        mx = fmaxf(mx, __shfl_xor(mx, 32));
        float m_new = fmaxf(m_run, mx);
        float m_use = (m_new == -__builtin_inff()) ? 0.f : m_new;
        float alpha = exp2f(m_run - m_use);
        float p[16], psum = 0.f;
        #pragma unroll
        for (int i2 = 0; i2 < 16; i2++) { p[i2] = exp2f(s[i2] - m_use); psum += p[i2]; }
        psum += __shfl_xor(psum, 16);
        psum += __shfl_xor(psum, 32);
        l_run = l_run * alpha + psum;
        m_run = m_new;
        #pragma unroll
        for (int ht = 0; ht < 4; ht++)
            #pragma unroll
            for (int r = 0; r < 4; r++) o[ht][r] *= alpha;

        // ---- P^T -> wave-private LDS as P[q][k] bf16 (intra-wave: no barrier)
        #pragma unroll
        for (int sub = 0; sub < 4; sub++) {
            unsigned int lo = (unsigned int)f2bf(p[sub * 4 + 0]) | ((unsigned int)f2bf(p[sub * 4 + 1]) << 16);
            unsigned int hi = (unsigned int)f2bf(p[sub * 4 + 2]) | ((unsigned int)f2bf(p[sub * 4 + 3]) << 16);
            *(uint2*)&pS[w][q16][sub * 16 + quad * 4] = make_uint2(lo, hi);
        }
        bf16x8 pf0 = *(const bf16x8*)&pS[w][q16][quad * 8];
        bf16x8 pf1 = *(const bf16x8*)&pS[w][q16][32 + quad * 8];

        // ---- O^T += V^T.P^T
        #pragma unroll
        for (int ht = 0; ht < 4; ht++) {
            o[ht] = __builtin_amdgcn_mfma_f32_16x16x32_bf16(vf[2 * ht],     pf0, o[ht], 0, 0, 0);
            o[ht] = __builtin_amdgcn_mfma_f32_16x16x32_bf16(vf[2 * ht + 1], pf1, o[ht], 0, 0, 0);
        }
    }

    // ---- merge the 4 waves' online-softmax states
    if (w > 0) {
        mlS[w - 1][lane][0] = m_run;
        mlS[w - 1][lane][1] = l_run;
        #pragma unroll
        for (int ht = 0; ht < 4; ht++)
            #pragma unroll
            for (int r = 0; r < 4; r++) oS[w - 1][lane][ht * 4 + r] = o[ht][r];
    }
    __syncthreads();
    if (w == 0) {
        float mm[3], ll[3];
        float m = m_run;
        #pragma unroll
        for (int j = 0; j < 3; j++) {
            mm[j] = mlS[j][lane][0]; ll[j] = mlS[j][lane][1];
            m = fmaxf(m, mm[j]);
        }
        float mu = (m == -__builtin_inff()) ? 0.f : m;
        float a0 = exp2f(m_run - mu);
        float aj[3];
        float l = l_run * a0;
        #pragma unroll
        for (int j = 0; j < 3; j++) { aj[j] = exp2f(mm[j] - mu); l += ll[j] * aj[j]; }
        float invl = (l > 0.f) ? (1.f / l) : 0.f;   // fully-masked row -> 0
        #pragma unroll
        for (int ht = 0; ht < 4; ht++) {
            float4 ov;
            float vx = o[ht][0] * a0, vy = o[ht][1] * a0, vz = o[ht][2] * a0, vw2 = o[ht][3] * a0;
            #pragma unroll
            for (int j = 0; j < 3; j++) {
                vx += oS[j][lane][ht * 4 + 0] * aj[j];
                vy += oS[j][lane][ht * 4 + 1] * aj[j];
                vz += oS[j][lane][ht * 4 + 2] * aj[j];
                vw2 += oS[j][lane][ht * 4 + 3] * aj[j];
            }
            ov.x = vx * invl; ov.y = vy * invl; ov.z = vz * invl; ov.w = vw2 * invl;
            *(float4*)(out + ((size_t)(b * T_) + qrow) * H_ + ht * 16 + quad * 4) = ov;
        }
    }
}

extern "C" void kernel_launch(void* const* d_in, const int* in_sizes, int n_in,
                              void* d_out, int out_size, void* d_ws, size_t ws_size,
                              hipStream_t stream) {
    const float* x    = (const float*)d_in[0];
    const float* mask = (const float*)d_in[1];
    const float* Wq   = (const float*)d_in[2];
    const float* Wk   = (const float*)d_in[3];
    const float* Wv   = (const float*)d_in[4];
    float* out = (float*)d_out;

    unsigned short* qw = (unsigned short*)d_ws;            // bf16 [B,T,H]
    unsigned short* kw = qw + (size_t)BT_ * H_;            // bf16 [B,T,H]
    unsigned short* vw = kw + (size_t)BT_ * H_;            // bf16 [B,H,T]
    unsigned short* wt = vw + (size_t)BT_ * H_;            // bf16 WTf[24][12][64][8]

    wprep<<<24, 256, 0, stream>>>(Wq, Wk, Wv, wt);
    qkv_kernel<<<BT_ / 16, 256, 0, stream>>>(x, wt, qw, kw, vw);
    attn_kernel<<<B_ * (T_ / 16), 256, 0, stream>>>(qw, kw, vw, mask, out);
}

// Round 11
// 122.747 us; speedup vs baseline: 1.3492x; 1.1770x over previous
//
#include <hip/hip_runtime.h>
#include <hip/hip_bf16.h>

#define B_ 8
#define T_ 2048
#define C_ 768
#define H_ 64
#define BT_ (B_*T_)

typedef __attribute__((ext_vector_type(8))) short bf16x8;
typedef __attribute__((ext_vector_type(4))) float f32x4;

__device__ __forceinline__ unsigned short f2bf(float x) {
    __hip_bfloat16 h = __float2bfloat16(x);   // RNE
    return __builtin_bit_cast(unsigned short, h);
}

__device__ __forceinline__ bf16x8 cvt8(float4 a, float4 b) {
    bf16x8 r;
    r[0] = (short)f2bf(a.x); r[1] = (short)f2bf(a.y);
    r[2] = (short)f2bf(a.z); r[3] = (short)f2bf(a.w);
    r[4] = (short)f2bf(b.x); r[5] = (short)f2bf(b.y);
    r[6] = (short)f2bf(b.z); r[7] = (short)f2bf(b.w);
    return r;
}

// ------------- W prep: emit W in EXACT MFMA A-fragment order ---------------------
// WTf[gc][f][lane][8]: consumer load = base + lane*16B (contiguous 1KB).
__global__ __launch_bounds__(256) void wprep(
    const float* __restrict__ Wq, const float* __restrict__ Wk,
    const float* __restrict__ Wv, unsigned short* __restrict__ WTf)
{
    const int gc = blockIdx.x;               // 0..23
    const int t  = threadIdx.x;
    const int lane = t >> 2;                 // 0..63
    const int j0   = (t & 3) * 2;            // 0,2,4,6
    const int q16  = lane & 15, quad = lane >> 4;
    const int k    = gc * 32 + quad * 8 + j0;
    #pragma unroll
    for (int f = 0; f < 12; f++) {
        const int row = f * 16 + q16;        // 0..191
        const int m = row >> 6, n = row & 63;
        const float* __restrict__ W = (m == 0) ? Wq : (m == 1) ? Wk : Wv;
        ushort2 u;
        u.x = f2bf(W[(size_t)k * H_ + n]);
        u.y = f2bf(W[(size_t)(k + 1) * H_ + n]);
        *(ushort2*)(WTf + (((size_t)gc * 12 + f) * 64 + lane) * 8 + j0) = u;
    }
}

// ------------- QKV via MFMA: 4-wave K-split; outputs FRAGMENT-PACKED ------------
// R10 confirmed gather-loads were the plateau (W fragment-ordering fixed qkv);
// attn has the same disease, so the epilogue now emits q/k/v in MFMA fragment
// order:
//   qF/kF[(tok_tile16)*2+half][lane][8]: elem j = X[token=lane&15]
//                                               [h=half*32+(lane>>4)*8+j]
//   vF[(tok_tile32)*4+ht][lane][8]:      elem j = V[token=(lane>>4)*8+j]
//                                               [h=ht*16+(lane&15)]
__global__ __launch_bounds__(256, 4) void qkv_kernel(
    const float* __restrict__ x, const unsigned short* __restrict__ WTf,
    unsigned short* __restrict__ qF, unsigned short* __restrict__ kF,
    unsigned short* __restrict__ vF)
{
    __shared__ float mrg[3][64][49];         // stride 49: odd -> 2-way banks (free)
    const int tid  = threadIdx.x;
    const int w    = tid >> 6;               // k-quarter 0..3
    const int lane = tid & 63;
    const int q16  = lane & 15, quad = lane >> 4;
    const int rowBase = blockIdx.x << 4;
    const int row  = rowBase + q16;

    const float* __restrict__ xp = x + (size_t)row * C_ + w * 192 + quad * 8;

    f32x4 acc[12] = {};
    #pragma unroll
    for (int c = 0; c < 6; c++) {
        const int gc = w * 6 + c;
        const unsigned short* __restrict__ wpc = WTf + ((size_t)gc * 12) * 512 + lane * 8;
        float4 xa = *(const float4*)(xp + c * 32);
        float4 xb = *(const float4*)(xp + c * 32 + 4);
        bf16x8 wf[12];
        #pragma unroll
        for (int f = 0; f < 12; f++)
            wf[f] = *(const bf16x8*)(wpc + f * 512);
        bf16x8 xf = cvt8(xa, xb);
        #pragma unroll
        for (int f = 0; f < 12; f++)
            acc[f] = __builtin_amdgcn_mfma_f32_16x16x32_bf16(wf[f], xf, acc[f], 0, 0, 0);
    }

    // ---- merge the four K-quarters (once per block)
    if (w > 0) {
        #pragma unroll
        for (int f = 0; f < 12; f++)
            #pragma unroll
            for (int r = 0; r < 4; r++) mrg[w - 1][lane][f * 4 + r] = acc[f][r];
    }
    __syncthreads();
    if (w == 0) {
        #pragma unroll
        for (int j = 0; j < 3; j++)
            #pragma unroll
            for (int f = 0; f < 12; f++)
                #pragma unroll
                for (int r = 0; r < 4; r++) acc[f][r] += mrg[j][lane][f * 4 + r];

        // ---- Q/K fragment-packed: acc[f][r] = OUT[token=q16][n=(f&3)*16+quad*4+r]
        // target elem (lane',j): OUT[lane'&15][h=half*32+(lane'>>4)*8+j]
        // h = (f&3)*16+quad*4+r -> half=(f&3)>>1, quad'=(2*(f&3)+(quad>>1))&3,
        // j = 4*(quad&1)+r  => one ushort4 store per f (verified bijective).
        const size_t gt = (size_t)(rowBase >> 4);
        #pragma unroll
        for (int f = 0; f < 8; f++) {
            ushort4 u;
            u.x = f2bf(acc[f][0]); u.y = f2bf(acc[f][1]);
            u.z = f2bf(acc[f][2]); u.w = f2bf(acc[f][3]);
            const int n4 = f & 3;
            const int qp = (2 * n4 + (quad >> 1)) & 3;
            const int j0 = (quad & 1) * 4;
            unsigned short* __restrict__ dst = (f < 4) ? qF : kF;
            *(ushort4*)(dst + ((gt * 2 + (n4 >> 1)) * 64 + q16 + 16 * qp) * 8 + j0) = u;
        }
        // ---- V fragment-packed: acc[f][r] = V[token=q16][h=(f-8)*16+quad*4+r]
        // target elem (lane',j): V[token32=(lane'>>4)*8+j][h=ht*16+(lane'&15)]
        const size_t g32 = (size_t)(rowBase >> 5);
        const int qv = ((rowBase >> 4) & 1) * 2 + (q16 >> 3);
        const int jv = q16 & 7;
        #pragma unroll
        for (int f = 8; f < 12; f++)
            #pragma unroll
            for (int r = 0; r < 4; r++)
                vF[((g32 * 4 + (f - 8)) * 64 + quad * 4 + r + 16 * qv) * 8 + jv] =
                    f2bf(acc[f][r]);
    }
}

// ------------- MFMA flash attention: 4-wave k-split, fragment-packed operands ---
// ALL inner-loop loads are now base + lane*16B (one contiguous 1KB region each).
__global__ __launch_bounds__(256) void attn_kernel(
    const unsigned short* __restrict__ qF, const unsigned short* __restrict__ kF,
    const unsigned short* __restrict__ vF, const float* __restrict__ mask,
    float* __restrict__ out)
{
    __shared__ __align__(16) unsigned short pS[4][16][88];  // wave-private P tiles
    __shared__ float oS[3][64][17];
    __shared__ float mlS[3][64][2];

    const int tid  = threadIdx.x;
    const int w    = tid >> 6;
    const int lane = tid & 63;
    const int q16  = lane & 15;
    const int quad = lane >> 4;
    const int bid  = blockIdx.x;
    const int b    = bid & 7;                    // batches interleaved
    const int qt   = 127 - (bid >> 3);           // heavy q-tiles first
    const int qrow = (qt << 4) + q16;

    const size_t qbase = ((size_t)(b * 128 + qt) * 2) * 512 + lane * 8;
    bf16x8 qf0 = *(const bf16x8*)(qF + qbase);
    bf16x8 qf1 = *(const bf16x8*)(qF + qbase + 512);
    // fold 1/sqrt(64) and log2(e): softmax runs in base-2 domain
    const float maskv = mask[b * T_ + qrow] * 0.125f * 1.44269504f;

    f32x4 o[4] = {};
    float m_run = -__builtin_inff();
    float l_run = 0.f;

    const int niter = ((qt << 4) + 16 + 63) >> 6;   // 64-wide k tiles
    for (int kt = w; kt < niter; kt += 4) {
        const int kbase = kt << 6;

        // ---- K and V fragment loads: all contiguous 1KB (lane*16B)
        bf16x8 kf[8], vf[8];
        #pragma unroll
        for (int sub = 0; sub < 4; sub++) {
            const unsigned short* kp = kF + ((size_t)(b * 128 + kt * 4 + sub) * 2) * 512 + lane * 8;
            kf[2 * sub]     = *(const bf16x8*)(kp);
            kf[2 * sub + 1] = *(const bf16x8*)(kp + 512);
        }
        #pragma unroll
        for (int ht = 0; ht < 4; ht++) {
            const unsigned short* vp = vF + ((size_t)(b * 64 + kt * 2) * 4 + ht) * 512 + lane * 8;
            vf[2 * ht]     = *(const bf16x8*)(vp);
            vf[2 * ht + 1] = *(const bf16x8*)(vp + 4 * 512);
        }

        // ---- S^T = K.Q^T : D[k_local][q]
        f32x4 sa[4] = {};
        #pragma unroll
        for (int sub = 0; sub < 4; sub++) {
            sa[sub] = __builtin_amdgcn_mfma_f32_16x16x32_bf16(kf[2 * sub],     qf0, sa[sub], 0, 0, 0);
            sa[sub] = __builtin_amdgcn_mfma_f32_16x16x32_bf16(kf[2 * sub + 1], qf1, sa[sub], 0, 0, 0);
        }

        // ---- reference semantics: s = mask*qk/8 (log2 dom); s==0 -> -inf; causal
        float s[16];
        #pragma unroll
        for (int sub = 0; sub < 4; sub++)
            #pragma unroll
            for (int r = 0; r < 4; r++) {
                int kidx = kbase + sub * 16 + quad * 4 + r;
                float sv = sa[sub][r] * maskv;
                sv = (sv == 0.f) ? -__builtin_inff() : sv;
                sv = (kidx > qrow) ? -__builtin_inff() : sv;
                s[sub * 4 + r] = sv;
            }

        // ---- online softmax (base-2). xor-16/32 reduce across the 4 lane-quads.
        float mx = s[0];
        #pragma unroll
        for (int i2 = 1; i2 < 16; i2++) mx = fmaxf(mx, s[i2]);
        mx = fmaxf(mx, __shfl_xor(mx, 16));
        mx = fmaxf(mx, __shfl_xor(mx, 32));
        float m_new = fmaxf(m_run, mx);
        float m_use = (m_new == -__builtin_inff()) ? 0.f : m_new;
        float alpha = exp2f(m_run - m_use);
        float p[16], psum = 0.f;
        #pragma unroll
        for (int i2 = 0; i2 < 16; i2++) { p[i2] = exp2f(s[i2] - m_use); psum += p[i2]; }
        psum += __shfl_xor(psum, 16);
        psum += __shfl_xor(psum, 32);
        l_run = l_run * alpha + psum;
        m_run = m_new;
        #pragma unroll
        for (int ht = 0; ht < 4; ht++)
            #pragma unroll
            for (int r = 0; r < 4; r++) o[ht][r] *= alpha;

        // ---- P^T -> wave-private LDS as P[q][k] bf16 (intra-wave: no barrier)
        #pragma unroll
        for (int sub = 0; sub < 4; sub++) {
            unsigned int lo = (unsigned int)f2bf(p[sub * 4 + 0]) | ((unsigned int)f2bf(p[sub * 4 + 1]) << 16);
            unsigned int hi = (unsigned int)f2bf(p[sub * 4 + 2]) | ((unsigned int)f2bf(p[sub * 4 + 3]) << 16);
            *(uint2*)&pS[w][q16][sub * 16 + quad * 4] = make_uint2(lo, hi);
        }
        bf16x8 pf0 = *(const bf16x8*)&pS[w][q16][quad * 8];
        bf16x8 pf1 = *(const bf16x8*)&pS[w][q16][32 + quad * 8];

        // ---- O^T += V^T.P^T
        #pragma unroll
        for (int ht = 0; ht < 4; ht++) {
            o[ht] = __builtin_amdgcn_mfma_f32_16x16x32_bf16(vf[2 * ht],     pf0, o[ht], 0, 0, 0);
            o[ht] = __builtin_amdgcn_mfma_f32_16x16x32_bf16(vf[2 * ht + 1], pf1, o[ht], 0, 0, 0);
        }
    }

    // ---- merge the 4 waves' online-softmax states
    if (w > 0) {
        mlS[w - 1][lane][0] = m_run;
        mlS[w - 1][lane][1] = l_run;
        #pragma unroll
        for (int ht = 0; ht < 4; ht++)
            #pragma unroll
            for (int r = 0; r < 4; r++) oS[w - 1][lane][ht * 4 + r] = o[ht][r];
    }
    __syncthreads();
    if (w == 0) {
        float mm[3], ll[3];
        float m = m_run;
        #pragma unroll
        for (int j = 0; j < 3; j++) {
            mm[j] = mlS[j][lane][0]; ll[j] = mlS[j][lane][1];
            m = fmaxf(m, mm[j]);
        }
        float mu = (m == -__builtin_inff()) ? 0.f : m;
        float a0 = exp2f(m_run - mu);
        float aj[3];
        float l = l_run * a0;
        #pragma unroll
        for (int j = 0; j < 3; j++) { aj[j] = exp2f(mm[j] - mu); l += ll[j] * aj[j]; }
        float invl = (l > 0.f) ? (1.f / l) : 0.f;   // fully-masked row -> 0
        #pragma unroll
        for (int ht = 0; ht < 4; ht++) {
            float4 ov;
            float vx = o[ht][0] * a0, vy = o[ht][1] * a0, vz = o[ht][2] * a0, vw2 = o[ht][3] * a0;
            #pragma unroll
            for (int j = 0; j < 3; j++) {
                vx += oS[j][lane][ht * 4 + 0] * aj[j];
                vy += oS[j][lane][ht * 4 + 1] * aj[j];
                vz += oS[j][lane][ht * 4 + 2] * aj[j];
                vw2 += oS[j][lane][ht * 4 + 3] * aj[j];
            }
            ov.x = vx * invl; ov.y = vy * invl; ov.z = vz * invl; ov.w = vw2 * invl;
            *(float4*)(out + ((size_t)(b * T_) + qrow) * H_ + ht * 16 + quad * 4) = ov;
        }
    }
}

extern "C" void kernel_launch(void* const* d_in, const int* in_sizes, int n_in,
                              void* d_out, int out_size, void* d_ws, size_t ws_size,
                              hipStream_t stream) {
    const float* x    = (const float*)d_in[0];
    const float* mask = (const float*)d_in[1];
    const float* Wq   = (const float*)d_in[2];
    const float* Wk   = (const float*)d_in[3];
    const float* Wv   = (const float*)d_in[4];
    float* out = (float*)d_out;

    unsigned short* qf = (unsigned short*)d_ws;            // bf16 frag-packed [BT*H]
    unsigned short* kf = qf + (size_t)BT_ * H_;
    unsigned short* vf = kf + (size_t)BT_ * H_;
    unsigned short* wt = vf + (size_t)BT_ * H_;            // bf16 WTf[24][12][64][8]

    wprep<<<24, 256, 0, stream>>>(Wq, Wk, Wv, wt);
    qkv_kernel<<<BT_ / 16, 256, 0, stream>>>(x, wt, qf, kf, vf);
    attn_kernel<<<B_ * (T_ / 16), 256, 0, stream>>>(qf, kf, vf, mask, out);
}

// Round 12
// 120.336 us; speedup vs baseline: 1.3762x; 1.0200x over previous
//
#include <hip/hip_runtime.h>
#include <hip/hip_bf16.h>

#define B_ 8
#define T_ 2048
#define C_ 768
#define H_ 64
#define BT_ (B_*T_)

typedef __attribute__((ext_vector_type(8))) short bf16x8;
typedef __attribute__((ext_vector_type(4))) float f32x4;

__device__ __forceinline__ unsigned short f2bf(float x) {
    __hip_bfloat16 h = __float2bfloat16(x);   // RNE
    return __builtin_bit_cast(unsigned short, h);
}

__device__ __forceinline__ bf16x8 cvt8(float4 a, float4 b) {
    bf16x8 r;
    r[0] = (short)f2bf(a.x); r[1] = (short)f2bf(a.y);
    r[2] = (short)f2bf(a.z); r[3] = (short)f2bf(a.w);
    r[4] = (short)f2bf(b.x); r[5] = (short)f2bf(b.y);
    r[6] = (short)f2bf(b.z); r[7] = (short)f2bf(b.w);
    return r;
}

// ------------- W prep (coalesced): block = (m, gc); LDS transpose ---------------
// WTf[gc][f][lane][8], elem j = W_m[k=gc*32+quad*8+j][n=(f%4)*16+q16].
// R10's 24-block scatter version did 147K strided 8B reads; this one is
// float4-coalesced in and ushort4-coalesced out.
__global__ __launch_bounds__(256) void wprep(
    const float* __restrict__ Wq, const float* __restrict__ Wk,
    const float* __restrict__ Wv, unsigned short* __restrict__ WTf)
{
    __shared__ float tile[32][68];           // 68: float4-aligned rows
    const int bid = blockIdx.x;              // 72 = 3 m * 24 gc
    const int m = bid / 24, gc = bid % 24;
    const float* __restrict__ W = (m == 0) ? Wq : (m == 1) ? Wk : Wv;
    const int t = threadIdx.x;
    {
        const int r = t >> 3, c0 = (t & 7) * 8;     // 8 threads x 8 floats = row of 64
        float4 a = *(const float4*)(W + (size_t)(gc * 32 + r) * H_ + c0);
        float4 b = *(const float4*)(W + (size_t)(gc * 32 + r) * H_ + c0 + 4);
        *(float4*)&tile[r][c0]     = a;
        *(float4*)&tile[r][c0 + 4] = b;
    }
    __syncthreads();
    const int fl = t >> 6, lane = t & 63;
    const int q16 = lane & 15, quad = lane >> 4;
    const int f = m * 4 + fl;
    ushort4 u0, u1;
    u0.x = f2bf(tile[quad * 8 + 0][fl * 16 + q16]);
    u0.y = f2bf(tile[quad * 8 + 1][fl * 16 + q16]);
    u0.z = f2bf(tile[quad * 8 + 2][fl * 16 + q16]);
    u0.w = f2bf(tile[quad * 8 + 3][fl * 16 + q16]);
    u1.x = f2bf(tile[quad * 8 + 4][fl * 16 + q16]);
    u1.y = f2bf(tile[quad * 8 + 5][fl * 16 + q16]);
    u1.z = f2bf(tile[quad * 8 + 6][fl * 16 + q16]);
    u1.w = f2bf(tile[quad * 8 + 7][fl * 16 + q16]);
    unsigned short* __restrict__ dst = WTf + ((size_t)(gc * 12 + f) * 64 + lane) * 8;
    *(ushort4*)(dst)     = u0;
    *(ushort4*)(dst + 4) = u1;
}

// ------------- QKV via MFMA: 4-wave K-split, 32 tokens/block, frag-packed out ---
// Wave w owns k-quarter w (6 chunks) for BOTH 16-token tiles: each W fragment
// feeds 2 MFMAs in-register -> W L2 traffic halves (295->147 MB) and per-chunk
// duty doubles (24 MFMA ~116cyc vs ~200cyc load latency; 2 waves/SIMD covers).
// Merge runs two phases over one 37.6KB LDS buffer.
__global__ __launch_bounds__(256, 2) void qkv_kernel(
    const float* __restrict__ x, const unsigned short* __restrict__ WTf,
    unsigned short* __restrict__ qF, unsigned short* __restrict__ kF,
    unsigned short* __restrict__ vF)
{
    __shared__ float mrg[3][64][49];         // stride 49 (odd): 2-way banks, free
    const int tid  = threadIdx.x;
    const int w    = tid >> 6;               // k-quarter 0..3
    const int lane = tid & 63;
    const int q16  = lane & 15, quad = lane >> 4;
    const int rowBase = blockIdx.x << 5;     // 32 tokens

    const float* __restrict__ xp0 = x + (size_t)(rowBase + q16) * C_ + w * 192 + quad * 8;
    const float* __restrict__ xp1 = xp0 + (size_t)16 * C_;

    f32x4 acc0[12] = {}, acc1[12] = {};
    #pragma unroll
    for (int c = 0; c < 6; c++) {
        const int gc = w * 6 + c;
        const unsigned short* __restrict__ wpc = WTf + ((size_t)gc * 12) * 512 + lane * 8;
        float4 xa0 = *(const float4*)(xp0 + c * 32);
        float4 xb0 = *(const float4*)(xp0 + c * 32 + 4);
        float4 xa1 = *(const float4*)(xp1 + c * 32);
        float4 xb1 = *(const float4*)(xp1 + c * 32 + 4);
        bf16x8 wf[12];
        #pragma unroll
        for (int f = 0; f < 12; f++)
            wf[f] = *(const bf16x8*)(wpc + f * 512);
        bf16x8 xf0 = cvt8(xa0, xb0);
        bf16x8 xf1 = cvt8(xa1, xb1);
        #pragma unroll
        for (int f = 0; f < 12; f++) {
            acc0[f] = __builtin_amdgcn_mfma_f32_16x16x32_bf16(wf[f], xf0, acc0[f], 0, 0, 0);
            acc1[f] = __builtin_amdgcn_mfma_f32_16x16x32_bf16(wf[f], xf1, acc1[f], 0, 0, 0);
        }
    }

    // ---- fragment-packed store of one 16-token tile (from R11, verified)
    auto flush = [&](f32x4* acc, int gtile) {
        const size_t gt = (size_t)gtile;
        #pragma unroll
        for (int f = 0; f < 8; f++) {
            ushort4 u;
            u.x = f2bf(acc[f][0]); u.y = f2bf(acc[f][1]);
            u.z = f2bf(acc[f][2]); u.w = f2bf(acc[f][3]);
            const int n4 = f & 3;
            const int qp = (2 * n4 + (quad >> 1)) & 3;
            const int j0 = (quad & 1) * 4;
            unsigned short* __restrict__ dst = (f < 4) ? qF : kF;
            *(ushort4*)(dst + ((gt * 2 + (n4 >> 1)) * 64 + q16 + 16 * qp) * 8 + j0) = u;
        }
        const size_t g32 = (size_t)(gtile >> 1);
        const int qv = (gtile & 1) * 2 + (q16 >> 3);
        const int jv = q16 & 7;
        #pragma unroll
        for (int f = 8; f < 12; f++)
            #pragma unroll
            for (int r = 0; r < 4; r++)
                vF[((g32 * 4 + (f - 8)) * 64 + quad * 4 + r + 16 * qv) * 8 + jv] =
                    f2bf(acc[f][r]);
    };

    // ---- two-phase merge over one LDS buffer
    if (w > 0) {
        #pragma unroll
        for (int f = 0; f < 12; f++)
            #pragma unroll
            for (int r = 0; r < 4; r++) mrg[w - 1][lane][f * 4 + r] = acc0[f][r];
    }
    __syncthreads();
    if (w == 0) {
        #pragma unroll
        for (int j = 0; j < 3; j++)
            #pragma unroll
            for (int f = 0; f < 12; f++)
                #pragma unroll
                for (int r = 0; r < 4; r++) acc0[f][r] += mrg[j][lane][f * 4 + r];
        flush(acc0, rowBase >> 4);
    }
    __syncthreads();
    if (w > 0) {
        #pragma unroll
        for (int f = 0; f < 12; f++)
            #pragma unroll
            for (int r = 0; r < 4; r++) mrg[w - 1][lane][f * 4 + r] = acc1[f][r];
    }
    __syncthreads();
    if (w == 0) {
        #pragma unroll
        for (int j = 0; j < 3; j++)
            #pragma unroll
            for (int f = 0; f < 12; f++)
                #pragma unroll
                for (int r = 0; r < 4; r++) acc1[f][r] += mrg[j][lane][f * 4 + r];
        flush(acc1, (rowBase >> 4) + 1);
    }
}

// ------------- MFMA flash attention: 4-wave k-split, fragment-packed operands ---
__global__ __launch_bounds__(256) void attn_kernel(
    const unsigned short* __restrict__ qF, const unsigned short* __restrict__ kF,
    const unsigned short* __restrict__ vF, const float* __restrict__ mask,
    float* __restrict__ out)
{
    __shared__ __align__(16) unsigned short pS[4][16][88];  // wave-private P tiles
    __shared__ float oS[3][64][17];
    __shared__ float mlS[3][64][2];

    const int tid  = threadIdx.x;
    const int w    = tid >> 6;
    const int lane = tid & 63;
    const int q16  = lane & 15;
    const int quad = lane >> 4;
    const int bid  = blockIdx.x;
    const int b    = bid & 7;                    // batches interleaved
    const int qt   = 127 - (bid >> 3);           // heavy q-tiles first
    const int qrow = (qt << 4) + q16;

    const size_t qbase = ((size_t)(b * 128 + qt) * 2) * 512 + lane * 8;
    bf16x8 qf0 = *(const bf16x8*)(qF + qbase);
    bf16x8 qf1 = *(const bf16x8*)(qF + qbase + 512);
    // fold 1/sqrt(64) and log2(e): softmax runs in base-2 domain
    const float maskv = mask[b * T_ + qrow] * 0.125f * 1.44269504f;

    f32x4 o[4] = {};
    float m_run = -__builtin_inff();
    float l_run = 0.f;

    const int niter = ((qt << 4) + 16 + 63) >> 6;   // 64-wide k tiles
    for (int kt = w; kt < niter; kt += 4) {
        const int kbase = kt << 6;

        // ---- K and V fragment loads: all contiguous 1KB (lane*16B)
        bf16x8 kf[8], vf[8];
        #pragma unroll
        for (int sub = 0; sub < 4; sub++) {
            const unsigned short* kp = kF + ((size_t)(b * 128 + kt * 4 + sub) * 2) * 512 + lane * 8;
            kf[2 * sub]     = *(const bf16x8*)(kp);
            kf[2 * sub + 1] = *(const bf16x8*)(kp + 512);
        }
        #pragma unroll
        for (int ht = 0; ht < 4; ht++) {
            const unsigned short* vp = vF + ((size_t)(b * 64 + kt * 2) * 4 + ht) * 512 + lane * 8;
            vf[2 * ht]     = *(const bf16x8*)(vp);
            vf[2 * ht + 1] = *(const bf16x8*)(vp + 4 * 512);
        }

        // ---- S^T = K.Q^T : D[k_local][q]
        f32x4 sa[4] = {};
        #pragma unroll
        for (int sub = 0; sub < 4; sub++) {
            sa[sub] = __builtin_amdgcn_mfma_f32_16x16x32_bf16(kf[2 * sub],     qf0, sa[sub], 0, 0, 0);
            sa[sub] = __builtin_amdgcn_mfma_f32_16x16x32_bf16(kf[2 * sub + 1], qf1, sa[sub], 0, 0, 0);
        }

        // ---- reference semantics: s = mask*qk/8 (log2 dom); s==0 -> -inf; causal
        float s[16];
        #pragma unroll
        for (int sub = 0; sub < 4; sub++)
            #pragma unroll
            for (int r = 0; r < 4; r++) {
                int kidx = kbase + sub * 16 + quad * 4 + r;
                float sv = sa[sub][r] * maskv;
                sv = (sv == 0.f) ? -__builtin_inff() : sv;
                sv = (kidx > qrow) ? -__builtin_inff() : sv;
                s[sub * 4 + r] = sv;
            }

        // ---- online softmax (base-2). xor-16/32 reduce across the 4 lane-quads.
        float mx = s[0];
        #pragma unroll
        for (int i2 = 1; i2 < 16; i2++) mx = fmaxf(mx, s[i2]);
        mx = fmaxf(mx, __shfl_xor(mx, 16));
        mx = fmaxf(mx, __shfl_xor(mx, 32));
        float m_new = fmaxf(m_run, mx);
        float m_use = (m_new == -__builtin_inff()) ? 0.f : m_new;
        float alpha = exp2f(m_run - m_use);
        float p[16], psum = 0.f;
        #pragma unroll
        for (int i2 = 0; i2 < 16; i2++) { p[i2] = exp2f(s[i2] - m_use); psum += p[i2]; }
        psum += __shfl_xor(psum, 16);
        psum += __shfl_xor(psum, 32);
        l_run = l_run * alpha + psum;
        m_run = m_new;
        #pragma unroll
        for (int ht = 0; ht < 4; ht++)
            #pragma unroll
            for (int r = 0; r < 4; r++) o[ht][r] *= alpha;

        // ---- P^T -> wave-private LDS as P[q][k] bf16 (intra-wave: no barrier)
        #pragma unroll
        for (int sub = 0; sub < 4; sub++) {
            unsigned int lo = (unsigned int)f2bf(p[sub * 4 + 0]) | ((unsigned int)f2bf(p[sub * 4 + 1]) << 16);
            unsigned int hi = (unsigned int)f2bf(p[sub * 4 + 2]) | ((unsigned int)f2bf(p[sub * 4 + 3]) << 16);
            *(uint2*)&pS[w][q16][sub * 16 + quad * 4] = make_uint2(lo, hi);
        }
        bf16x8 pf0 = *(const bf16x8*)&pS[w][q16][quad * 8];
        bf16x8 pf1 = *(const bf16x8*)&pS[w][q16][32 + quad * 8];

        // ---- O^T += V^T.P^T
        #pragma unroll
        for (int ht = 0; ht < 4; ht++) {
            o[ht] = __builtin_amdgcn_mfma_f32_16x16x32_bf16(vf[2 * ht],     pf0, o[ht], 0, 0, 0);
            o[ht] = __builtin_amdgcn_mfma_f32_16x16x32_bf16(vf[2 * ht + 1], pf1, o[ht], 0, 0, 0);
        }
    }

    // ---- merge the 4 waves' online-softmax states
    if (w > 0) {
        mlS[w - 1][lane][0] = m_run;
        mlS[w - 1][lane][1] = l_run;
        #pragma unroll
        for (int ht = 0; ht < 4; ht++)
            #pragma unroll
            for (int r = 0; r < 4; r++) oS[w - 1][lane][ht * 4 + r] = o[ht][r];
    }
    __syncthreads();
    if (w == 0) {
        float mm[3], ll[3];
        float m = m_run;
        #pragma unroll
        for (int j = 0; j < 3; j++) {
            mm[j] = mlS[j][lane][0]; ll[j] = mlS[j][lane][1];
            m = fmaxf(m, mm[j]);
        }
        float mu = (m == -__builtin_inff()) ? 0.f : m;
        float a0 = exp2f(m_run - mu);
        float aj[3];
        float l = l_run * a0;
        #pragma unroll
        for (int j = 0; j < 3; j++) { aj[j] = exp2f(mm[j] - mu); l += ll[j] * aj[j]; }
        float invl = (l > 0.f) ? (1.f / l) : 0.f;   // fully-masked row -> 0
        #pragma unroll
        for (int ht = 0; ht < 4; ht++) {
            float4 ov;
            float vx = o[ht][0] * a0, vy = o[ht][1] * a0, vz = o[ht][2] * a0, vw2 = o[ht][3] * a0;
            #pragma unroll
            for (int j = 0; j < 3; j++) {
                vx += oS[j][lane][ht * 4 + 0] * aj[j];
                vy += oS[j][lane][ht * 4 + 1] * aj[j];
                vz += oS[j][lane][ht * 4 + 2] * aj[j];
                vw2 += oS[j][lane][ht * 4 + 3] * aj[j];
            }
            ov.x = vx * invl; ov.y = vy * invl; ov.z = vz * invl; ov.w = vw2 * invl;
            *(float4*)(out + ((size_t)(b * T_) + qrow) * H_ + ht * 16 + quad * 4) = ov;
        }
    }
}

extern "C" void kernel_launch(void* const* d_in, const int* in_sizes, int n_in,
                              void* d_out, int out_size, void* d_ws, size_t ws_size,
                              hipStream_t stream) {
    const float* x    = (const float*)d_in[0];
    const float* mask = (const float*)d_in[1];
    const float* Wq   = (const float*)d_in[2];
    const float* Wk   = (const float*)d_in[3];
    const float* Wv   = (const float*)d_in[4];
    float* out = (float*)d_out;

    unsigned short* qf = (unsigned short*)d_ws;            // bf16 frag-packed [BT*H]
    unsigned short* kf = qf + (size_t)BT_ * H_;
    unsigned short* vf = kf + (size_t)BT_ * H_;
    unsigned short* wt = vf + (size_t)BT_ * H_;            // bf16 WTf[24][12][64][8]

    wprep<<<72, 256, 0, stream>>>(Wq, Wk, Wv, wt);
    qkv_kernel<<<BT_ / 32, 256, 0, stream>>>(x, wt, qf, kf, vf);
    attn_kernel<<<B_ * (T_ / 16), 256, 0, stream>>>(qf, kf, vf, mask, out);
}

// Round 13
// 118.115 us; speedup vs baseline: 1.4021x; 1.0188x over previous
//
#include <hip/hip_runtime.h>
#include <hip/hip_bf16.h>

#define B_ 8
#define T_ 2048
#define C_ 768
#define H_ 64
#define BT_ (B_*T_)

typedef __attribute__((ext_vector_type(8))) short bf16x8;
typedef __attribute__((ext_vector_type(4))) float f32x4;

__device__ __forceinline__ unsigned short f2bf(float x) {
    __hip_bfloat16 h = __float2bfloat16(x);   // RNE
    return __builtin_bit_cast(unsigned short, h);
}

__device__ __forceinline__ bf16x8 cvt8(float4 a, float4 b) {
    bf16x8 r;
    r[0] = (short)f2bf(a.x); r[1] = (short)f2bf(a.y);
    r[2] = (short)f2bf(a.z); r[3] = (short)f2bf(a.w);
    r[4] = (short)f2bf(b.x); r[5] = (short)f2bf(b.y);
    r[6] = (short)f2bf(b.z); r[7] = (short)f2bf(b.w);
    return r;
}

// ------------- W prep (coalesced): block = (m, gc); LDS transpose ---------------
__global__ __launch_bounds__(256) void wprep(
    const float* __restrict__ Wq, const float* __restrict__ Wk,
    const float* __restrict__ Wv, unsigned short* __restrict__ WTf)
{
    __shared__ float tile[32][68];
    const int bid = blockIdx.x;              // 72 = 3 m * 24 gc
    const int m = bid / 24, gc = bid % 24;
    const float* __restrict__ W = (m == 0) ? Wq : (m == 1) ? Wk : Wv;
    const int t = threadIdx.x;
    {
        const int r = t >> 3, c0 = (t & 7) * 8;
        float4 a = *(const float4*)(W + (size_t)(gc * 32 + r) * H_ + c0);
        float4 b = *(const float4*)(W + (size_t)(gc * 32 + r) * H_ + c0 + 4);
        *(float4*)&tile[r][c0]     = a;
        *(float4*)&tile[r][c0 + 4] = b;
    }
    __syncthreads();
    const int fl = t >> 6, lane = t & 63;
    const int q16 = lane & 15, quad = lane >> 4;
    const int f = m * 4 + fl;
    ushort4 u0, u1;
    u0.x = f2bf(tile[quad * 8 + 0][fl * 16 + q16]);
    u0.y = f2bf(tile[quad * 8 + 1][fl * 16 + q16]);
    u0.z = f2bf(tile[quad * 8 + 2][fl * 16 + q16]);
    u0.w = f2bf(tile[quad * 8 + 3][fl * 16 + q16]);
    u1.x = f2bf(tile[quad * 8 + 4][fl * 16 + q16]);
    u1.y = f2bf(tile[quad * 8 + 5][fl * 16 + q16]);
    u1.z = f2bf(tile[quad * 8 + 6][fl * 16 + q16]);
    u1.w = f2bf(tile[quad * 8 + 7][fl * 16 + q16]);
    unsigned short* __restrict__ dst = WTf + ((size_t)(gc * 12 + f) * 64 + lane) * 8;
    *(ushort4*)(dst)     = u0;
    *(ushort4*)(dst + 4) = u1;
}

// ------------- QKV via MFMA: 16 tokens/block, 4-wave K-split, LDS-staged x ------
// The LAST gather in the pipeline was the per-wave x fragment load (16 rows,
// 3KB apart, per instruction). Now the block's contiguous 48KB x slab is staged
// to LDS bf16 with fully-coalesced global reads; compute x reads become single
// ds_read_b128 (row stride 772 shorts: reader banks (2*q16+4*quad)%32 -> <=2-way
// = free). xS and mrg share one 37.6KB LDS allocation (disjoint lifetimes) so
// 4 blocks/CU still fit.
__global__ __launch_bounds__(256, 4) void qkv_kernel(
    const float* __restrict__ x, const unsigned short* __restrict__ WTf,
    unsigned short* __restrict__ qF, unsigned short* __restrict__ kF,
    unsigned short* __restrict__ vF)
{
    __shared__ __align__(16) char shraw[3 * 64 * 49 * 4];   // 37632 B union
    unsigned short* xS = (unsigned short*)shraw;            // [16][772] bf16
    float (*mrg)[64][49] = (float (*)[64][49])shraw;        // [3][64][49] f32

    const int tid  = threadIdx.x;
    const int w    = tid >> 6;               // k-quarter 0..3
    const int lane = tid & 63;
    const int q16  = lane & 15, quad = lane >> 4;
    const int rowBase = blockIdx.x << 4;

    // ---- stage x: thread t = (row t>>4, l=t&15); 6 x 32B contiguous per thread
    {
        const int r = tid >> 4, l = tid & 15;
        const float* __restrict__ xrow = x + (size_t)(rowBase + r) * C_;
        #pragma unroll
        for (int i = 0; i < 6; i++) {
            const int j = i * 16 + l;        // 32B granule 0..95
            float4 a = *(const float4*)(xrow + j * 8);
            float4 b = *(const float4*)(xrow + j * 8 + 4);
            *(bf16x8*)&xS[(size_t)r * 772 + j * 8] = cvt8(a, b);
        }
    }
    __syncthreads();

    // ---- compute: wave w owns chunks gc = w*6..w*6+5
    const unsigned short* __restrict__ xrowS = xS + q16 * 772 + w * 192 + quad * 8;
    f32x4 acc[12] = {};
    #pragma unroll
    for (int c = 0; c < 6; c++) {
        const int gc = w * 6 + c;
        const unsigned short* __restrict__ wpc = WTf + ((size_t)gc * 12) * 512 + lane * 8;
        bf16x8 xf = *(const bf16x8*)(xrowS + c * 32);
        bf16x8 wf[12];
        #pragma unroll
        for (int f = 0; f < 12; f++)
            wf[f] = *(const bf16x8*)(wpc + f * 512);
        #pragma unroll
        for (int f = 0; f < 12; f++)
            acc[f] = __builtin_amdgcn_mfma_f32_16x16x32_bf16(wf[f], xf, acc[f], 0, 0, 0);
    }
    __syncthreads();                          // xS dead after this; mrg may begin

    // ---- merge the four K-quarters
    if (w > 0) {
        #pragma unroll
        for (int f = 0; f < 12; f++)
            #pragma unroll
            for (int r = 0; r < 4; r++) mrg[w - 1][lane][f * 4 + r] = acc[f][r];
    }
    __syncthreads();
    if (w == 0) {
        #pragma unroll
        for (int j = 0; j < 3; j++)
            #pragma unroll
            for (int f = 0; f < 12; f++)
                #pragma unroll
                for (int r = 0; r < 4; r++) acc[f][r] += mrg[j][lane][f * 4 + r];

        // ---- fragment-packed epilogue (R11, verified)
        const size_t gt = (size_t)(rowBase >> 4);
        #pragma unroll
        for (int f = 0; f < 8; f++) {
            ushort4 u;
            u.x = f2bf(acc[f][0]); u.y = f2bf(acc[f][1]);
            u.z = f2bf(acc[f][2]); u.w = f2bf(acc[f][3]);
            const int n4 = f & 3;
            const int qp = (2 * n4 + (quad >> 1)) & 3;
            const int j0 = (quad & 1) * 4;
            unsigned short* __restrict__ dst = (f < 4) ? qF : kF;
            *(ushort4*)(dst + ((gt * 2 + (n4 >> 1)) * 64 + q16 + 16 * qp) * 8 + j0) = u;
        }
        const size_t g32 = gt >> 1;
        const int qv = ((int)gt & 1) * 2 + (q16 >> 3);
        const int jv = q16 & 7;
        #pragma unroll
        for (int f = 8; f < 12; f++)
            #pragma unroll
            for (int r = 0; r < 4; r++)
                vF[((g32 * 4 + (f - 8)) * 64 + quad * 4 + r + 16 * qv) * 8 + jv] =
                    f2bf(acc[f][r]);
    }
}

// ------------- MFMA flash attention: 4-wave k-split, fragment-packed operands ---
__global__ __launch_bounds__(256) void attn_kernel(
    const unsigned short* __restrict__ qF, const unsigned short* __restrict__ kF,
    const unsigned short* __restrict__ vF, const float* __restrict__ mask,
    float* __restrict__ out)
{
    __shared__ __align__(16) unsigned short pS[4][16][88];  // wave-private P tiles
    __shared__ float oS[3][64][17];
    __shared__ float mlS[3][64][2];

    const int tid  = threadIdx.x;
    const int w    = tid >> 6;
    const int lane = tid & 63;
    const int q16  = lane & 15;
    const int quad = lane >> 4;
    const int bid  = blockIdx.x;
    const int b    = bid & 7;                    // batches interleaved
    const int qt   = 127 - (bid >> 3);           // heavy q-tiles first
    const int qrow = (qt << 4) + q16;

    const size_t qbase = ((size_t)(b * 128 + qt) * 2) * 512 + lane * 8;
    bf16x8 qf0 = *(const bf16x8*)(qF + qbase);
    bf16x8 qf1 = *(const bf16x8*)(qF + qbase + 512);
    // fold 1/sqrt(64) and log2(e): softmax runs in base-2 domain
    const float maskv = mask[b * T_ + qrow] * 0.125f * 1.44269504f;

    f32x4 o[4] = {};
    float m_run = -__builtin_inff();
    float l_run = 0.f;

    const int niter = ((qt << 4) + 16 + 63) >> 6;   // 64-wide k tiles
    for (int kt = w; kt < niter; kt += 4) {
        const int kbase = kt << 6;

        // ---- K and V fragment loads: all contiguous 1KB (lane*16B)
        bf16x8 kf[8], vf[8];
        #pragma unroll
        for (int sub = 0; sub < 4; sub++) {
            const unsigned short* kp = kF + ((size_t)(b * 128 + kt * 4 + sub) * 2) * 512 + lane * 8;
            kf[2 * sub]     = *(const bf16x8*)(kp);
            kf[2 * sub + 1] = *(const bf16x8*)(kp + 512);
        }
        #pragma unroll
        for (int ht = 0; ht < 4; ht++) {
            const unsigned short* vp = vF + ((size_t)(b * 64 + kt * 2) * 4 + ht) * 512 + lane * 8;
            vf[2 * ht]     = *(const bf16x8*)(vp);
            vf[2 * ht + 1] = *(const bf16x8*)(vp + 4 * 512);
        }

        // ---- S^T = K.Q^T : D[k_local][q]
        f32x4 sa[4] = {};
        #pragma unroll
        for (int sub = 0; sub < 4; sub++) {
            sa[sub] = __builtin_amdgcn_mfma_f32_16x16x32_bf16(kf[2 * sub],     qf0, sa[sub], 0, 0, 0);
            sa[sub] = __builtin_amdgcn_mfma_f32_16x16x32_bf16(kf[2 * sub + 1], qf1, sa[sub], 0, 0, 0);
        }

        // ---- reference semantics: s = mask*qk/8 (log2 dom); s==0 -> -inf; causal
        float s[16];
        #pragma unroll
        for (int sub = 0; sub < 4; sub++)
            #pragma unroll
            for (int r = 0; r < 4; r++) {
                int kidx = kbase + sub * 16 + quad * 4 + r;
                float sv = sa[sub][r] * maskv;
                sv = (sv == 0.f) ? -__builtin_inff() : sv;
                sv = (kidx > qrow) ? -__builtin_inff() : sv;
                s[sub * 4 + r] = sv;
            }

        // ---- online softmax (base-2). xor-16/32 reduce across the 4 lane-quads.
        float mx = s[0];
        #pragma unroll
        for (int i2 = 1; i2 < 16; i2++) mx = fmaxf(mx, s[i2]);
        mx = fmaxf(mx, __shfl_xor(mx, 16));
        mx = fmaxf(mx, __shfl_xor(mx, 32));
        float m_new = fmaxf(m_run, mx);
        float m_use = (m_new == -__builtin_inff()) ? 0.f : m_new;
        float alpha = exp2f(m_run - m_use);
        float p[16], psum = 0.f;
        #pragma unroll
        for (int i2 = 0; i2 < 16; i2++) { p[i2] = exp2f(s[i2] - m_use); psum += p[i2]; }
        psum += __shfl_xor(psum, 16);
        psum += __shfl_xor(psum, 32);
        l_run = l_run * alpha + psum;
        m_run = m_new;
        #pragma unroll
        for (int ht = 0; ht < 4; ht++)
            #pragma unroll
            for (int r = 0; r < 4; r++) o[ht][r] *= alpha;

        // ---- P^T -> wave-private LDS as P[q][k] bf16 (intra-wave: no barrier)
        #pragma unroll
        for (int sub = 0; sub < 4; sub++) {
            unsigned int lo = (unsigned int)f2bf(p[sub * 4 + 0]) | ((unsigned int)f2bf(p[sub * 4 + 1]) << 16);
            unsigned int hi = (unsigned int)f2bf(p[sub * 4 + 2]) | ((unsigned int)f2bf(p[sub * 4 + 3]) << 16);
            *(uint2*)&pS[w][q16][sub * 16 + quad * 4] = make_uint2(lo, hi);
        }
        bf16x8 pf0 = *(const bf16x8*)&pS[w][q16][quad * 8];
        bf16x8 pf1 = *(const bf16x8*)&pS[w][q16][32 + quad * 8];

        // ---- O^T += V^T.P^T
        #pragma unroll
        for (int ht = 0; ht < 4; ht++) {
            o[ht] = __builtin_amdgcn_mfma_f32_16x16x32_bf16(vf[2 * ht],     pf0, o[ht], 0, 0, 0);
            o[ht] = __builtin_amdgcn_mfma_f32_16x16x32_bf16(vf[2 * ht + 1], pf1, o[ht], 0, 0, 0);
        }
    }

    // ---- merge the 4 waves' online-softmax states
    if (w > 0) {
        mlS[w - 1][lane][0] = m_run;
        mlS[w - 1][lane][1] = l_run;
        #pragma unroll
        for (int ht = 0; ht < 4; ht++)
            #pragma unroll
            for (int r = 0; r < 4; r++) oS[w - 1][lane][ht * 4 + r] = o[ht][r];
    }
    __syncthreads();
    if (w == 0) {
        float mm[3], ll[3];
        float m = m_run;
        #pragma unroll
        for (int j = 0; j < 3; j++) {
            mm[j] = mlS[j][lane][0]; ll[j] = mlS[j][lane][1];
            m = fmaxf(m, mm[j]);
        }
        float mu = (m == -__builtin_inff()) ? 0.f : m;
        float a0 = exp2f(m_run - mu);
        float aj[3];
        float l = l_run * a0;
        #pragma unroll
        for (int j = 0; j < 3; j++) { aj[j] = exp2f(mm[j] - mu); l += ll[j] * aj[j]; }
        float invl = (l > 0.f) ? (1.f / l) : 0.f;   // fully-masked row -> 0
        #pragma unroll
        for (int ht = 0; ht < 4; ht++) {
            float4 ov;
            float vx = o[ht][0] * a0, vy = o[ht][1] * a0, vz = o[ht][2] * a0, vw2 = o[ht][3] * a0;
            #pragma unroll
            for (int j = 0; j < 3; j++) {
                vx += oS[j][lane][ht * 4 + 0] * aj[j];
                vy += oS[j][lane][ht * 4 + 1] * aj[j];
                vz += oS[j][lane][ht * 4 + 2] * aj[j];
                vw2 += oS[j][lane][ht * 4 + 3] * aj[j];
            }
            ov.x = vx * invl; ov.y = vy * invl; ov.z = vz * invl; ov.w = vw2 * invl;
            *(float4*)(out + ((size_t)(b * T_) + qrow) * H_ + ht * 16 + quad * 4) = ov;
        }
    }
}

extern "C" void kernel_launch(void* const* d_in, const int* in_sizes, int n_in,
                              void* d_out, int out_size, void* d_ws, size_t ws_size,
                              hipStream_t stream) {
    const float* x    = (const float*)d_in[0];
    const float* mask = (const float*)d_in[1];
    const float* Wq   = (const float*)d_in[2];
    const float* Wk   = (const float*)d_in[3];
    const float* Wv   = (const float*)d_in[4];
    float* out = (float*)d_out;

    unsigned short* qf = (unsigned short*)d_ws;            // bf16 frag-packed [BT*H]
    unsigned short* kf = qf + (size_t)BT_ * H_;
    unsigned short* vf = kf + (size_t)BT_ * H_;
    unsigned short* wt = vf + (size_t)BT_ * H_;            // bf16 WTf[24][12][64][8]

    wprep<<<72, 256, 0, stream>>>(Wq, Wk, Wv, wt);
    qkv_kernel<<<BT_ / 16, 256, 0, stream>>>(x, wt, qf, kf, vf);
    attn_kernel<<<B_ * (T_ / 16), 256, 0, stream>>>(qf, kf, vf, mask, out);
}